// Round 10
// baseline (8898.547 us; speedup 1.0000x reference)
//
#include <hip/hip_runtime.h>

// NeuralCDE: B=64,T=256,C=16,S=64,H=128. fp32 recursion (f16 decorrelates).
// R4 20.4ms stream-everything. R5 62ms cross-block sync poison. R6-R9: the
// register-residency plan was defeated 3x by the allocator (64/128-reg caps,
// remat, silent reload) — VGPR_Count stuck at 128, stage stuck ~5.7us.
// R10: pin weights in AGPRs via asm("" : "+a"(x)). No load-to-AGPR path
// exists, so reload/remat is impossible; CDNA2+ VALU reads AGPRs directly.
// Pinned (200 AGPR): W0 slice 16 + W1 slice 32 + W2 rows 2tid,2tid+1 cols
// 0..75 (152). Streamed/stage: W2 cols 76..89 (28 transient VGPRs, 57KB L2,
// hidden under h1/h2). LDS: W2 cols 90..127 col-major [38][1024] (2-way
// aliasing = free). Budget: 200 AGPR + ~56 VGPR = 256/wave at 8 waves/CU.
// Readout/SO(3) moved OFF the serial path: y-states -> d_ws, second kernel.
// Fast HW transcendentals (v_exp/v_log/v_rcp): ~3e-7 rel, budget-safe.

typedef float float4v __attribute__((ext_vector_type(4)));
typedef float float2v __attribute__((ext_vector_type(2)));

__device__ __forceinline__ float dot4(float4v a, float4v b) {
  return a.x * b.x + a.y * b.y + a.z * b.z + a.w * b.w;
}

__device__ __forceinline__ float softplus_fast(float x) {
  // max(x,0) + log(1+exp(-|x|)); v_exp/v_log are ~1ulp, log1p->log ok here
  float z = __expf(-fabsf(x));
  return fmaxf(x, 0.f) + __logf(1.f + z);
}

__device__ __forceinline__ float tanh_hw(float x) {
  float e = __expf(2.f * x);  // inf-safe: e=inf -> 1; e=0 -> -1
  return 1.f - 2.f * __builtin_amdgcn_rcpf(e + 1.f);
}

__global__ __launch_bounds__(512, 1) void cde_main(
    const float* __restrict__ xs,
    const float* __restrict__ icw0, const float* __restrict__ icb0,
    const float* __restrict__ icw1, const float* __restrict__ icb1,
    const float* __restrict__ icw2, const float* __restrict__ icb2,
    const float* __restrict__ vfw0, const float* __restrict__ vfb0,
    const float* __restrict__ vfw1, const float* __restrict__ vfb1,
    const float* __restrict__ vfw2, const float* __restrict__ vfb2,
    float* __restrict__ ybuf) {
  constexpr float Ac[6][5] = {
      {0.f, 0.f, 0.f, 0.f, 0.f},
      {0.161f, 0.f, 0.f, 0.f, 0.f},
      {-0.008480655492356989f, 0.335480655492357f, 0.f, 0.f, 0.f},
      {2.8971530571054935f, -6.359448489975075f, 4.3622954328695815f, 0.f, 0.f},
      {5.325864828439257f, -11.748883564062828f, 7.4955393428898365f,
       -0.09249506636175525f, 0.f},
      {5.86145544294642f, -12.92096931784711f, 8.159367898576159f,
       -0.071584973281401f, -0.028269050394068383f}};
  constexpr float SCv[6] = {0.f, 0.161f, 0.327f, 0.9f, 0.9800255409045097f, 1.f};
  constexpr float BWv[6] = {0.09646076681806523f, 0.01f, 0.4798896504144996f,
                            1.379008574103742f, -3.290069515436081f,
                            2.324710524099774f};

  const int tid = threadIdx.x;
  const int b = blockIdx.x;  // one block per batch element

  __shared__ float sW2t[38][1024];  // W2 cols 90..127 col-major
  __shared__ __align__(16) float sYt[64];
  __shared__ __align__(16) float sH1[128];
  __shared__ __align__(16) float sH2[128];
  __shared__ float sDx[16];
  __shared__ float sK[6][64];

  // ---- one-time: resident weights, pinned into AGPRs ----
  const int r0 = tid * 2, r1 = r0 + 1;  // W2 rows owned
  float w2a[76], w2b[76];               // cols 0..75 of rows r0,r1
  {
    const float4v* p0 = (const float4v*)(vfw2 + (size_t)r0 * 128);
    const float4v* p1 = (const float4v*)(vfw2 + (size_t)r1 * 128);
#pragma unroll
    for (int kk = 0; kk < 19; ++kk) {
      float4v a = p0[kk], c = p1[kk];
      w2a[4 * kk + 0] = a.x; w2a[4 * kk + 1] = a.y;
      w2a[4 * kk + 2] = a.z; w2a[4 * kk + 3] = a.w;
      w2b[4 * kk + 0] = c.x; w2b[4 * kk + 1] = c.y;
      w2b[4 * kk + 2] = c.z; w2b[4 * kk + 3] = c.w;
    }
  }
#pragma unroll
  for (int kk = 0; kk < 76; ++kk)
    asm volatile("" : "+a"(w2a[kk]), "+a"(w2b[kk]));

  const int ii = tid >> 2, q4 = tid & 3;  // h1/h2: 4 lanes per output
  float w0r[16], w1r[32];
  {
    const float4v* p = (const float4v*)(vfw0 + (size_t)ii * 64 + q4 * 16);
#pragma unroll
    for (int kk = 0; kk < 4; ++kk) {
      float4v a = p[kk];
      w0r[4 * kk] = a.x; w0r[4 * kk + 1] = a.y;
      w0r[4 * kk + 2] = a.z; w0r[4 * kk + 3] = a.w;
    }
  }
  {
    const float4v* p = (const float4v*)(vfw1 + (size_t)ii * 128 + q4 * 32);
#pragma unroll
    for (int kk = 0; kk < 8; ++kk) {
      float4v a = p[kk];
      w1r[4 * kk] = a.x; w1r[4 * kk + 1] = a.y;
      w1r[4 * kk + 2] = a.z; w1r[4 * kk + 3] = a.w;
    }
  }
#pragma unroll
  for (int kk = 0; kk < 16; ++kk) asm volatile("" : "+a"(w0r[kk]));
#pragma unroll
  for (int kk = 0; kk < 32; ++kk) asm volatile("" : "+a"(w1r[kk]));

  // ---- one-time: LDS W2 tail columns ----
  for (int i = tid; i < 38 * 1024; i += 512) {
    int k = i >> 10, r = i & 1023;
    sW2t[k][r] = vfw2[(size_t)r * 128 + 90 + k];
  }

  const float b2r0 = vfb2[r0], b2r1 = vfb2[r1];
  const int c0 = r0 & 15;  // dx channel of row r0 (even); r1 -> c0+1
  const float b0i = vfb0[ii], b1i = vfb1[ii];

  const float* Xb = xs + (size_t)b * 4096;
  float* yb = ybuf + (size_t)b * 256 * 64;

  __syncthreads();

  // ---- initial condition MLP (one-time; sTA := sK[0..], sTB := sH1) ----
  float* sTA = &sK[0][0];
  float* sTB = sH1;
  if (tid < 128) {
    float a = icb0[tid];
    const float* wr = icw0 + tid * 16;
#pragma unroll
    for (int k = 0; k < 16; ++k) a += wr[k] * Xb[k];
    sTA[tid] = softplus_fast(a);
  }
  __syncthreads();
  if (tid < 128) {
    float a = icb1[tid];
    const float* wr = icw1 + tid * 128;
    for (int k = 0; k < 128; ++k) a += wr[k] * sTA[k];
    sTB[tid] = softplus_fast(a);
  }
  __syncthreads();
  float yreg = 0.f;  // valid on lanes 0..63 (wave 0)
  if (tid < 64) {
    float a = icb2[tid];
    const float* wr = icw2 + tid * 128;
    for (int k = 0; k < 128; ++k) a += wr[k] * sTB[k];
    yreg = a;
    yb[tid] = a;  // y state at t=0
  }
  __syncthreads();  // sTA/sTB aliases done before sK/sH1 reused

  const float hstep = 1.f / 255.f;
  const float invh = 255.f;

#pragma unroll 1
  for (int t = 0; t < 255; ++t) {
    float xi = 0.f, xip1 = 0.f, di = 0.f, dip1 = 0.f;  // lanes 64..79
    if (tid >= 64 && tid < 80) {
      int c = tid - 64;
      xi = Xb[t * 16 + c];
      xip1 = Xb[(t + 1) * 16 + c];
      dip1 = (xip1 - xi) * invh;
      di = (t == 0) ? dip1 : (xi - Xb[(t - 1) * 16 + c]) * invh;
    }
#pragma unroll 1
    for (int j = 0; j < 6; ++j) {
      // ---- streamed W2 cols 76..89 (issued now, used in k-phase) ----
      const float* wr0 = vfw2 + (size_t)r0 * 128;
      const float* wr1 = vfw2 + (size_t)r1 * 128;
      float4v sa0 = *(const float4v*)(wr0 + 76);
      float4v sa1 = *(const float4v*)(wr0 + 80);
      float4v sa2 = *(const float4v*)(wr0 + 84);
      float2v sa3 = *(const float2v*)(wr0 + 88);
      float4v sb0 = *(const float4v*)(wr1 + 76);
      float4v sb1 = *(const float4v*)(wr1 + 80);
      float4v sb2 = *(const float4v*)(wr1 + 84);
      float2v sb3 = *(const float2v*)(wr1 + 88);
      // ---- phase 0: stage input y_j (wave 0) and dXdt(sc_j) (wave 1) ----
      if (tid < 64) {
        float yt = yreg;
#pragma unroll
        for (int m = 0; m < 5; ++m)
          if (m < j) yt += hstep * Ac[j][m] * sK[m][tid];
        sYt[tid] = yt;
      } else if (tid < 80) {
        float sc = SCv[j];
        float s2 = sc * sc;
        float d1 = (6.f * s2 - 6.f * sc) * invh;
        float d2 = 3.f * s2 - 4.f * sc + 1.f;
        float d4 = 3.f * s2 - 2.f * sc;
        sDx[tid - 64] = d1 * (xi - xip1) + d2 * di + d4 * dip1;
      }
      __syncthreads();
      // ---- h1 = softplus(W0 @ y + b0): W0 pinned in AGPRs ----
      {
        const float4v* yv = (const float4v*)(sYt + q4 * 16);
        float4v y0 = yv[0], y1 = yv[1], y2 = yv[2], y3 = yv[3];
        float s = w0r[0] * y0.x + w0r[1] * y0.y + w0r[2] * y0.z +
                  w0r[3] * y0.w + w0r[4] * y1.x + w0r[5] * y1.y +
                  w0r[6] * y1.z + w0r[7] * y1.w + w0r[8] * y2.x +
                  w0r[9] * y2.y + w0r[10] * y2.z + w0r[11] * y2.w +
                  w0r[12] * y3.x + w0r[13] * y3.y + w0r[14] * y3.z +
                  w0r[15] * y3.w;
        s += __shfl_xor(s, 1);
        s += __shfl_xor(s, 2);
        if (q4 == 0) sH1[ii] = softplus_fast(s + b0i);
      }
      __syncthreads();
      // ---- h2 = softplus(W1 @ h1 + b1): W1 pinned in AGPRs ----
      {
        const float4v* hv = (const float4v*)(sH1 + q4 * 32);
        float s = 0.f;
#pragma unroll
        for (int kk = 0; kk < 8; ++kk) {
          float4v h = hv[kk];
          s += w1r[4 * kk] * h.x + w1r[4 * kk + 1] * h.y +
               w1r[4 * kk + 2] * h.z + w1r[4 * kk + 3] * h.w;
        }
        s += __shfl_xor(s, 1);
        s += __shfl_xor(s, 2);
        if (q4 == 0) sH2[ii] = softplus_fast(s + b1i);
      }
      __syncthreads();
      // ---- k: rows r0,r1 of A = tanh(W2 h2 + b2), * dx, reduce over c ----
      {
        const float4v* hv = (const float4v*)sH2;
        float s0 = 0.f, s1 = 0.f;
#pragma unroll
        for (int kk = 0; kk < 19; ++kk) {  // pinned cols 0..75
          float4v h = hv[kk];
          s0 += w2a[4 * kk] * h.x + w2a[4 * kk + 1] * h.y +
                w2a[4 * kk + 2] * h.z + w2a[4 * kk + 3] * h.w;
          s1 += w2b[4 * kk] * h.x + w2b[4 * kk + 1] * h.y +
                w2b[4 * kk + 2] * h.z + w2b[4 * kk + 3] * h.w;
        }
        {  // streamed cols 76..89
          float4v h0 = hv[19], h1 = hv[20], h2 = hv[21];
          float2v h3 = *(const float2v*)(sH2 + 88);
          s0 += dot4(sa0, h0) + dot4(sa1, h1) + dot4(sa2, h2) +
                sa3.x * h3.x + sa3.y * h3.y;
          s1 += dot4(sb0, h0) + dot4(sb1, h1) + dot4(sb2, h2) +
                sb3.x * h3.x + sb3.y * h3.y;
        }
#pragma unroll 4
        for (int k2 = 0; k2 < 19; ++k2) {  // LDS cols 90..127, pairwise
          float2v hk = *(const float2v*)(sH2 + 90 + 2 * k2);
          float2v wlo = *(const float2v*)&sW2t[2 * k2][r0];
          float2v whi = *(const float2v*)&sW2t[2 * k2 + 1][r0];
          s0 += wlo.x * hk.x + whi.x * hk.y;
          s1 += wlo.y * hk.x + whi.y * hk.y;
        }
        float f = tanh_hw(s0 + b2r0) * sDx[c0] + tanh_hw(s1 + b2r1) * sDx[c0 + 1];
        f += __shfl_xor(f, 1);
        f += __shfl_xor(f, 2);
        f += __shfl_xor(f, 4);
        if ((tid & 7) == 0) sK[j][tid >> 3] = f;
      }
      __syncthreads();
    }
    // ---- y_{t+1} = y_t + h * sum BW_m k_m; dump state (fire-and-forget) --
    if (tid < 64) {
      float yn = yreg;
#pragma unroll
      for (int m = 0; m < 6; ++m) yn += hstep * BWv[m] * sK[m][tid];
      yreg = yn;
      yb[(size_t)(t + 1) * 64 + tid] = yn;
    }
  }
}

// Parallel readout: one thread per (b,t): out6 = y @ ro^T + rob, 6D->SO(3).
__global__ __launch_bounds__(256) void readout(
    const float* __restrict__ ybuf, const float* __restrict__ row,
    const float* __restrict__ rob, float* __restrict__ out) {
  int idx = blockIdx.x * blockDim.x + threadIdx.x;  // 0..16383 = b*256+t
  const float* y = ybuf + (size_t)idx * 64;
  float p[6];
#pragma unroll
  for (int o = 0; o < 6; ++o) {
    const float4v* rr = (const float4v*)(row + o * 64);
    const float4v* yv = (const float4v*)y;
    float s = 0.f;
#pragma unroll
    for (int k = 0; k < 16; ++k) s += dot4(rr[k], yv[k]);
    p[o] = s + rob[o];
  }
  float a1x = p[0], a1y = p[1], a1z = p[2];
  float a2x = p[3], a2y = p[4], a2z = p[5];
  float n1 = rsqrtf(a1x * a1x + a1y * a1y + a1z * a1z);
  float b1x = a1x * n1, b1y = a1y * n1, b1z = a1z * n1;
  float d = b1x * a2x + b1y * a2y + b1z * a2z;
  float px = a2x - d * b1x, py = a2y - d * b1y, pz = a2z - d * b1z;
  float n2 = rsqrtf(px * px + py * py + pz * pz);
  float b2x = px * n2, b2y = py * n2, b2z = pz * n2;
  float b3x = b1y * b2z - b1z * b2y;
  float b3y = b1z * b2x - b1x * b2z;
  float b3z = b1x * b2y - b1y * b2x;
  float* o = out + (size_t)idx * 9;
  o[0] = b1x; o[1] = b2x; o[2] = b3x;
  o[3] = b1y; o[4] = b2y; o[5] = b3y;
  o[6] = b1z; o[7] = b2z; o[8] = b3z;
}

extern "C" void kernel_launch(void* const* d_in, const int* in_sizes, int n_in,
                              void* d_out, int out_size, void* d_ws,
                              size_t ws_size, hipStream_t stream) {
  (void)in_sizes; (void)n_in; (void)out_size; (void)ws_size;
  const float* xs   = (const float*)d_in[0];
  const float* icw0 = (const float*)d_in[1];
  const float* icb0 = (const float*)d_in[2];
  const float* icw1 = (const float*)d_in[3];
  const float* icb1 = (const float*)d_in[4];
  const float* icw2 = (const float*)d_in[5];
  const float* icb2 = (const float*)d_in[6];
  const float* vfw0 = (const float*)d_in[7];
  const float* vfb0 = (const float*)d_in[8];
  const float* vfw1 = (const float*)d_in[9];
  const float* vfb1 = (const float*)d_in[10];
  const float* vfw2 = (const float*)d_in[11];
  const float* vfb2 = (const float*)d_in[12];
  const float* row  = (const float*)d_in[13];
  const float* rob  = (const float*)d_in[14];
  float* ybuf = (float*)d_ws;  // 64*256*64 floats = 4 MB

  hipLaunchKernelGGL(cde_main, dim3(64), dim3(512), 0, stream,
                     xs, icw0, icb0, icw1, icb1, icw2, icb2,
                     vfw0, vfb0, vfw1, vfb1, vfw2, vfb2, ybuf);
  hipLaunchKernelGGL(readout, dim3(64), dim3(256), 0, stream,
                     ybuf, row, rob, (float*)d_out);
}

// Round 11
// 6636.040 us; speedup vs baseline: 1.3409x; 1.3409x over previous
//
#include <hip/hip_runtime.h>

// NeuralCDE: B=64,T=256,C=16,S=64,H=128. fp32 recursion (f16 decorrelates).
// R4 20.4ms full-stream; R5 62ms cross-block sync poison; R6-R10: three
// residency mechanisms (caps/remat/reload, v-pin, a-pin) all leave stage time
// at 5.7-5.9us; gfx950 unified RF silently converts "a" pins to "v".
// R11 discriminating experiment: attack per-stage LATENCY, storage as R10.
//  - 3 barriers/stage (was 4): y_j + dXdt computed redundantly per-wave into
//    wave-private LDS (in-wave lgkmcnt wait only, no cross-wave dep).
//  - dXdt fully in registers (per-lane channel pair, j-invariant basis).
//  - per-step y-update redundant per-wave; only wave0 dumps states.
// If latency-bound -> ~2-3.5us/stage; if flat -> L2 re-stream is the floor.

typedef float float4v __attribute__((ext_vector_type(4)));
typedef float float2v __attribute__((ext_vector_type(2)));

__device__ __forceinline__ float dot4(float4v a, float4v b) {
  return a.x * b.x + a.y * b.y + a.z * b.z + a.w * b.w;
}

__device__ __forceinline__ float softplus_fast(float x) {
  float z = __expf(-fabsf(x));
  return fmaxf(x, 0.f) + __logf(1.f + z);
}

__device__ __forceinline__ float tanh_hw(float x) {
  float e = __expf(2.f * x);  // inf-safe
  return 1.f - 2.f * __builtin_amdgcn_rcpf(e + 1.f);
}

__global__ __launch_bounds__(512, 1) void cde_main(
    const float* __restrict__ xs,
    const float* __restrict__ icw0, const float* __restrict__ icb0,
    const float* __restrict__ icw1, const float* __restrict__ icb1,
    const float* __restrict__ icw2, const float* __restrict__ icb2,
    const float* __restrict__ vfw0, const float* __restrict__ vfb0,
    const float* __restrict__ vfw1, const float* __restrict__ vfb1,
    const float* __restrict__ vfw2, const float* __restrict__ vfb2,
    float* __restrict__ ybuf) {
  constexpr float Ac[6][5] = {
      {0.f, 0.f, 0.f, 0.f, 0.f},
      {0.161f, 0.f, 0.f, 0.f, 0.f},
      {-0.008480655492356989f, 0.335480655492357f, 0.f, 0.f, 0.f},
      {2.8971530571054935f, -6.359448489975075f, 4.3622954328695815f, 0.f, 0.f},
      {5.325864828439257f, -11.748883564062828f, 7.4955393428898365f,
       -0.09249506636175525f, 0.f},
      {5.86145544294642f, -12.92096931784711f, 8.159367898576159f,
       -0.071584973281401f, -0.028269050394068383f}};
  constexpr float SCv[6] = {0.f, 0.161f, 0.327f, 0.9f, 0.9800255409045097f, 1.f};
  constexpr float BWv[6] = {0.09646076681806523f, 0.01f, 0.4798896504144996f,
                            1.379008574103742f, -3.290069515436081f,
                            2.324710524099774f};

  const int tid = threadIdx.x;
  const int w = tid >> 6, l = tid & 63;
  const int b = blockIdx.x;  // one block per batch element

  __shared__ float sW2t[38][1024];              // W2 cols 90..127 col-major
  __shared__ __align__(16) float sYtw[8][64];   // wave-private stage inputs
  __shared__ __align__(16) float sH1[128];
  __shared__ __align__(16) float sH2[128];
  __shared__ float sK[6][64];

  // ---- one-time: LDS W2 tail columns ----
  for (int i = tid; i < 38 * 1024; i += 512) {
    int k = i >> 10, r = i & 1023;
    sW2t[k][r] = vfw2[(size_t)r * 128 + 90 + k];
  }

  // ---- one-time: resident weights (pins kept from R10; harmless) ----
  const int r0 = tid * 2, r1 = r0 + 1;  // W2 rows owned
  float w2a[76], w2b[76];               // cols 0..75
  {
    const float4v* p0 = (const float4v*)(vfw2 + (size_t)r0 * 128);
    const float4v* p1 = (const float4v*)(vfw2 + (size_t)r1 * 128);
#pragma unroll
    for (int kk = 0; kk < 19; ++kk) {
      float4v a = p0[kk], c = p1[kk];
      w2a[4 * kk + 0] = a.x; w2a[4 * kk + 1] = a.y;
      w2a[4 * kk + 2] = a.z; w2a[4 * kk + 3] = a.w;
      w2b[4 * kk + 0] = c.x; w2b[4 * kk + 1] = c.y;
      w2b[4 * kk + 2] = c.z; w2b[4 * kk + 3] = c.w;
    }
  }
#pragma unroll
  for (int kk = 0; kk < 76; ++kk)
    asm volatile("" : "+v"(w2a[kk]), "+v"(w2b[kk]));

  const int ii = tid >> 2, q4 = tid & 3;  // h1/h2: 4 lanes per output
  float w0r[16], w1r[32];
  {
    const float4v* p = (const float4v*)(vfw0 + (size_t)ii * 64 + q4 * 16);
#pragma unroll
    for (int kk = 0; kk < 4; ++kk) {
      float4v a = p[kk];
      w0r[4 * kk] = a.x; w0r[4 * kk + 1] = a.y;
      w0r[4 * kk + 2] = a.z; w0r[4 * kk + 3] = a.w;
    }
  }
  {
    const float4v* p = (const float4v*)(vfw1 + (size_t)ii * 128 + q4 * 32);
#pragma unroll
    for (int kk = 0; kk < 8; ++kk) {
      float4v a = p[kk];
      w1r[4 * kk] = a.x; w1r[4 * kk + 1] = a.y;
      w1r[4 * kk + 2] = a.z; w1r[4 * kk + 3] = a.w;
    }
  }
#pragma unroll
  for (int kk = 0; kk < 16; ++kk) asm volatile("" : "+v"(w0r[kk]));
#pragma unroll
  for (int kk = 0; kk < 32; ++kk) asm volatile("" : "+v"(w1r[kk]));

  const float b2r0 = vfb2[r0], b2r1 = vfb2[r1];
  const int c0 = (2 * l) & 15;  // even dx channel of row r0; r1 -> c0+1
  const float b0i = vfb0[ii], b1i = vfb1[ii];

  const float* Xb = xs + (size_t)b * 4096;
  float* yb = ybuf + (size_t)b * 16384;

  __syncthreads();

  // ---- initial condition MLP (one-time; sTA := sK[0..1], sTB := sH1) ----
  float* sTA = &sK[0][0];
  float* sTB = sH1;
  if (tid < 128) {
    float a = icb0[tid];
    const float* wr = icw0 + tid * 16;
#pragma unroll
    for (int k = 0; k < 16; ++k) a += wr[k] * Xb[k];
    sTA[tid] = softplus_fast(a);
  }
  __syncthreads();
  if (tid < 128) {
    float a = icb1[tid];
    const float* wr = icw1 + tid * 128;
    for (int k = 0; k < 128; ++k) a += wr[k] * sTA[k];
    sTB[tid] = softplus_fast(a);
  }
  __syncthreads();
  if (tid < 64) {
    float a = icb2[tid];
    const float* wr = icw2 + tid * 128;
    for (int k = 0; k < 128; ++k) a += wr[k] * sTB[k];
    sH2[tid] = a;  // temp broadcast slot
  }
  __syncthreads();
  float yreg = sH2[l];  // every wave holds y[l]
  if (w == 0) yb[l] = yreg;

  const float hstep = 1.f / 255.f;
  const float invh = 255.f;

#pragma unroll 1
  for (int t = 0; t < 255; ++t) {
    // per-lane x-channel pair (c0, c0+1): j-invariant dXdt basis in regs
    float2v xt = *(const float2v*)(Xb + t * 16 + c0);
    float2v xt1 = *(const float2v*)(Xb + (t + 1) * 16 + c0);
    float2v xtm = xt;
    if (t != 0) xtm = *(const float2v*)(Xb + (t - 1) * 16 + c0);
    const float u0 = xt.x - xt1.x, u1 = xt.y - xt1.y;          // (xi - xip1)
    const float dp0 = (xt1.x - xt.x) * invh;                    // dfull[t+1]
    const float dp1 = (xt1.y - xt.y) * invh;
    float di0 = (t == 0) ? dp0 : (xt.x - xtm.x) * invh;         // dfull[t]
    float di1 = (t == 0) ? dp1 : (xt.y - xtm.y) * invh;
#pragma unroll 1
    for (int j = 0; j < 6; ++j) {
      // ---- streamed W2 cols 76..89 (consumed in k-phase) ----
      const float* wr0 = vfw2 + (size_t)r0 * 128;
      const float* wr1 = vfw2 + (size_t)r1 * 128;
      float4v sa0 = *(const float4v*)(wr0 + 76);
      float4v sa1 = *(const float4v*)(wr0 + 80);
      float4v sa2 = *(const float4v*)(wr0 + 84);
      float2v sa3 = *(const float2v*)(wr0 + 88);
      float4v sb0 = *(const float4v*)(wr1 + 76);
      float4v sb1 = *(const float4v*)(wr1 + 80);
      float4v sb2 = *(const float4v*)(wr1 + 84);
      float2v sb3 = *(const float2v*)(wr1 + 88);
      // ---- stage input y_j: every wave, per-lane, wave-private buffer ----
      {
        float yt = yreg;
#pragma unroll
        for (int m = 0; m < 5; ++m)
          if (m < j) yt += hstep * Ac[j][m] * sK[m][l];
        sYtw[w][l] = yt;
      }
      asm volatile("s_waitcnt lgkmcnt(0)" ::: "memory");  // in-wave only
      // ---- dXdt(sc_j) in registers ----
      const float sc = SCv[j], s2 = sc * sc;
      const float a1 = (6.f * s2 - 6.f * sc) * invh;
      const float a2 = 3.f * s2 - 4.f * sc + 1.f;
      const float a3 = 3.f * s2 - 2.f * sc;
      const float dx0 = a1 * u0 + a2 * di0 + a3 * dp0;
      const float dx1 = a1 * u1 + a2 * di1 + a3 * dp1;
      // ---- h1 = softplus(W0 @ y + b0) ----
      {
        const float4v* yv = (const float4v*)(&sYtw[w][0] + q4 * 16);
        float4v y0 = yv[0], y1 = yv[1], y2 = yv[2], y3 = yv[3];
        float s = w0r[0] * y0.x + w0r[1] * y0.y + w0r[2] * y0.z +
                  w0r[3] * y0.w + w0r[4] * y1.x + w0r[5] * y1.y +
                  w0r[6] * y1.z + w0r[7] * y1.w + w0r[8] * y2.x +
                  w0r[9] * y2.y + w0r[10] * y2.z + w0r[11] * y2.w +
                  w0r[12] * y3.x + w0r[13] * y3.y + w0r[14] * y3.z +
                  w0r[15] * y3.w;
        s += __shfl_xor(s, 1);
        s += __shfl_xor(s, 2);
        if (q4 == 0) sH1[ii] = softplus_fast(s + b0i);
      }
      __syncthreads();
      // ---- h2 = softplus(W1 @ h1 + b1) ----
      {
        const float4v* hv = (const float4v*)(sH1 + q4 * 32);
        float s = 0.f;
#pragma unroll
        for (int kk = 0; kk < 8; ++kk) {
          float4v h = hv[kk];
          s += w1r[4 * kk] * h.x + w1r[4 * kk + 1] * h.y +
               w1r[4 * kk + 2] * h.z + w1r[4 * kk + 3] * h.w;
        }
        s += __shfl_xor(s, 1);
        s += __shfl_xor(s, 2);
        if (q4 == 0) sH2[ii] = softplus_fast(s + b1i);
      }
      __syncthreads();
      // ---- k: rows r0,r1 of A = tanh(W2 h2 + b2), * dx, reduce over c ----
      {
        const float4v* hv = (const float4v*)sH2;
        float s0 = 0.f, s1 = 0.f;
#pragma unroll
        for (int kk = 0; kk < 19; ++kk) {  // cols 0..75
          float4v h = hv[kk];
          s0 += w2a[4 * kk] * h.x + w2a[4 * kk + 1] * h.y +
                w2a[4 * kk + 2] * h.z + w2a[4 * kk + 3] * h.w;
          s1 += w2b[4 * kk] * h.x + w2b[4 * kk + 1] * h.y +
                w2b[4 * kk + 2] * h.z + w2b[4 * kk + 3] * h.w;
        }
        {  // streamed cols 76..89
          float4v h0 = hv[19], h1 = hv[20], h2 = hv[21];
          float2v h3 = *(const float2v*)(sH2 + 88);
          s0 += dot4(sa0, h0) + dot4(sa1, h1) + dot4(sa2, h2) +
                sa3.x * h3.x + sa3.y * h3.y;
          s1 += dot4(sb0, h0) + dot4(sb1, h1) + dot4(sb2, h2) +
                sb3.x * h3.x + sb3.y * h3.y;
        }
#pragma unroll 4
        for (int k2 = 0; k2 < 19; ++k2) {  // LDS cols 90..127, pairwise
          float2v hk = *(const float2v*)(sH2 + 90 + 2 * k2);
          float2v wlo = *(const float2v*)&sW2t[2 * k2][r0];
          float2v whi = *(const float2v*)&sW2t[2 * k2 + 1][r0];
          s0 += wlo.x * hk.x + whi.x * hk.y;
          s1 += wlo.y * hk.x + whi.y * hk.y;
        }
        float f = tanh_hw(s0 + b2r0) * dx0 + tanh_hw(s1 + b2r1) * dx1;
        f += __shfl_xor(f, 1);
        f += __shfl_xor(f, 2);
        f += __shfl_xor(f, 4);
        if ((tid & 7) == 0) sK[j][tid >> 3] = f;
      }
      __syncthreads();
    }
    // ---- y_{t+1}: every wave redundantly; wave0 dumps the state ----
    {
      float yn = yreg;
#pragma unroll
      for (int m = 0; m < 6; ++m) yn += hstep * BWv[m] * sK[m][l];
      yreg = yn;
      if (w == 0) yb[(size_t)(t + 1) * 64 + l] = yn;
    }
    // next stage-0 reads no sK; sK[0] rewritten only after 2 barriers. safe.
  }
}

// Parallel readout: one thread per (b,t): out6 = y @ ro^T + rob, 6D->SO(3).
__global__ __launch_bounds__(256) void readout(
    const float* __restrict__ ybuf, const float* __restrict__ row,
    const float* __restrict__ rob, float* __restrict__ out) {
  int idx = blockIdx.x * blockDim.x + threadIdx.x;  // b*256+t
  const float* y = ybuf + (size_t)idx * 64;
  float p[6];
#pragma unroll
  for (int o = 0; o < 6; ++o) {
    const float4v* rr = (const float4v*)(row + o * 64);
    const float4v* yv = (const float4v*)y;
    float s = 0.f;
#pragma unroll
    for (int k = 0; k < 16; ++k) s += dot4(rr[k], yv[k]);
    p[o] = s + rob[o];
  }
  float a1x = p[0], a1y = p[1], a1z = p[2];
  float a2x = p[3], a2y = p[4], a2z = p[5];
  float n1 = rsqrtf(a1x * a1x + a1y * a1y + a1z * a1z);
  float b1x = a1x * n1, b1y = a1y * n1, b1z = a1z * n1;
  float d = b1x * a2x + b1y * a2y + b1z * a2z;
  float px = a2x - d * b1x, py = a2y - d * b1y, pz = a2z - d * b1z;
  float n2 = rsqrtf(px * px + py * py + pz * pz);
  float b2x = px * n2, b2y = py * n2, b2z = pz * n2;
  float b3x = b1y * b2z - b1z * b2y;
  float b3y = b1z * b2x - b1x * b2z;
  float b3z = b1x * b2y - b1y * b2x;
  float* o = out + (size_t)idx * 9;
  o[0] = b1x; o[1] = b2x; o[2] = b3x;
  o[3] = b1y; o[4] = b2y; o[5] = b3y;
  o[6] = b1z; o[7] = b2z; o[8] = b3z;
}

extern "C" void kernel_launch(void* const* d_in, const int* in_sizes, int n_in,
                              void* d_out, int out_size, void* d_ws,
                              size_t ws_size, hipStream_t stream) {
  (void)in_sizes; (void)n_in; (void)out_size; (void)ws_size;
  const float* xs   = (const float*)d_in[0];
  const float* icw0 = (const float*)d_in[1];
  const float* icb0 = (const float*)d_in[2];
  const float* icw1 = (const float*)d_in[3];
  const float* icb1 = (const float*)d_in[4];
  const float* icw2 = (const float*)d_in[5];
  const float* icb2 = (const float*)d_in[6];
  const float* vfw0 = (const float*)d_in[7];
  const float* vfb0 = (const float*)d_in[8];
  const float* vfw1 = (const float*)d_in[9];
  const float* vfb1 = (const float*)d_in[10];
  const float* vfw2 = (const float*)d_in[11];
  const float* vfb2 = (const float*)d_in[12];
  const float* row  = (const float*)d_in[13];
  const float* rob  = (const float*)d_in[14];
  float* ybuf = (float*)d_ws;  // 64*256*64 floats = 4 MB

  hipLaunchKernelGGL(cde_main, dim3(64), dim3(512), 0, stream,
                     xs, icw0, icb0, icw1, icb1, icw2, icb2,
                     vfw0, vfb0, vfw1, vfb1, vfw2, vfb2, ybuf);
  hipLaunchKernelGGL(readout, dim3(64), dim3(256), 0, stream,
                     ybuf, row, rob, (float*)d_out);
}

// Round 12
// 6523.622 us; speedup vs baseline: 1.3641x; 1.0172x over previous
//
#include <hip/hip_runtime.h>

// NeuralCDE: B=64,T=256,C=16,S=64,H=128. fp32 recursion (f16 decorrelates).
// R11 6.64ms: 3-barrier stage; VGPR stuck at 128 across 5 rounds -> pins
// dropped, W2 bulk (304KB/stage) still re-read from L2 (~2us, invisible in
// FETCH_SIZE which is HBM-only). Compiler ignores launch_bounds for reg
// budget; R12 tries the dedicated attribute amdgpu_waves_per_eu(2,2):
// exactly 2 waves/EU -> 256 VGPR/wave budget (8 waves = full 2048 file).
// Honest budget: pinned W2 rows 2tid,2tid+1 cols 0..71 (144) + W0 (16) +
// W1 (32) = 192; streamed cols 72..89/stage (36 transient, 74KB L2);
// LDS cols 90..127 ([38][1024] col-major, stride-2 = free 2-way).
// SIGNATURE: VGPR_Count -> ~250 means granted; 128 means hard cap, pivot.

typedef float float4v __attribute__((ext_vector_type(4)));
typedef float float2v __attribute__((ext_vector_type(2)));

__device__ __forceinline__ float dot4(float4v a, float4v b) {
  return a.x * b.x + a.y * b.y + a.z * b.z + a.w * b.w;
}

__device__ __forceinline__ float softplus_fast(float x) {
  float z = __expf(-fabsf(x));
  return fmaxf(x, 0.f) + __logf(1.f + z);
}

__device__ __forceinline__ float tanh_hw(float x) {
  float e = __expf(2.f * x);  // inf-safe
  return 1.f - 2.f * __builtin_amdgcn_rcpf(e + 1.f);
}

__global__ __attribute__((amdgpu_waves_per_eu(2, 2)))
__launch_bounds__(512, 1) void cde_main(
    const float* __restrict__ xs,
    const float* __restrict__ icw0, const float* __restrict__ icb0,
    const float* __restrict__ icw1, const float* __restrict__ icb1,
    const float* __restrict__ icw2, const float* __restrict__ icb2,
    const float* __restrict__ vfw0, const float* __restrict__ vfb0,
    const float* __restrict__ vfw1, const float* __restrict__ vfb1,
    const float* __restrict__ vfw2, const float* __restrict__ vfb2,
    float* __restrict__ ybuf) {
  constexpr float Ac[6][5] = {
      {0.f, 0.f, 0.f, 0.f, 0.f},
      {0.161f, 0.f, 0.f, 0.f, 0.f},
      {-0.008480655492356989f, 0.335480655492357f, 0.f, 0.f, 0.f},
      {2.8971530571054935f, -6.359448489975075f, 4.3622954328695815f, 0.f, 0.f},
      {5.325864828439257f, -11.748883564062828f, 7.4955393428898365f,
       -0.09249506636175525f, 0.f},
      {5.86145544294642f, -12.92096931784711f, 8.159367898576159f,
       -0.071584973281401f, -0.028269050394068383f}};
  constexpr float SCv[6] = {0.f, 0.161f, 0.327f, 0.9f, 0.9800255409045097f, 1.f};
  constexpr float BWv[6] = {0.09646076681806523f, 0.01f, 0.4798896504144996f,
                            1.379008574103742f, -3.290069515436081f,
                            2.324710524099774f};

  const int tid = threadIdx.x;
  const int w = tid >> 6, l = tid & 63;
  const int b = blockIdx.x;  // one block per batch element

  __shared__ float sW2t[38][1024];              // W2 cols 90..127 col-major
  __shared__ __align__(16) float sYtw[8][64];   // wave-private stage inputs
  __shared__ __align__(16) float sH1[128];
  __shared__ __align__(16) float sH2[128];
  __shared__ float sK[6][64];

  // ---- one-time: LDS W2 tail columns ----
  for (int i = tid; i < 38 * 1024; i += 512) {
    int k = i >> 10, r = i & 1023;
    sW2t[k][r] = vfw2[(size_t)r * 128 + 90 + k];
  }

  // ---- one-time: resident weights, pinned (cols 0..71 of rows r0,r1) ----
  const int r0 = tid * 2, r1 = r0 + 1;
  float w2a[72], w2b[72];
  {
    const float4v* p0 = (const float4v*)(vfw2 + (size_t)r0 * 128);
    const float4v* p1 = (const float4v*)(vfw2 + (size_t)r1 * 128);
#pragma unroll
    for (int kk = 0; kk < 18; ++kk) {
      float4v a = p0[kk], c = p1[kk];
      w2a[4 * kk + 0] = a.x; w2a[4 * kk + 1] = a.y;
      w2a[4 * kk + 2] = a.z; w2a[4 * kk + 3] = a.w;
      w2b[4 * kk + 0] = c.x; w2b[4 * kk + 1] = c.y;
      w2b[4 * kk + 2] = c.z; w2b[4 * kk + 3] = c.w;
    }
  }
#pragma unroll
  for (int kk = 0; kk < 72; ++kk)
    asm volatile("" : "+v"(w2a[kk]), "+v"(w2b[kk]));

  const int ii = tid >> 2, q4 = tid & 3;  // h1/h2: 4 lanes per output
  float w0r[16], w1r[32];
  {
    const float4v* p = (const float4v*)(vfw0 + (size_t)ii * 64 + q4 * 16);
#pragma unroll
    for (int kk = 0; kk < 4; ++kk) {
      float4v a = p[kk];
      w0r[4 * kk] = a.x; w0r[4 * kk + 1] = a.y;
      w0r[4 * kk + 2] = a.z; w0r[4 * kk + 3] = a.w;
    }
  }
  {
    const float4v* p = (const float4v*)(vfw1 + (size_t)ii * 128 + q4 * 32);
#pragma unroll
    for (int kk = 0; kk < 8; ++kk) {
      float4v a = p[kk];
      w1r[4 * kk] = a.x; w1r[4 * kk + 1] = a.y;
      w1r[4 * kk + 2] = a.z; w1r[4 * kk + 3] = a.w;
    }
  }
#pragma unroll
  for (int kk = 0; kk < 16; ++kk) asm volatile("" : "+v"(w0r[kk]));
#pragma unroll
  for (int kk = 0; kk < 32; ++kk) asm volatile("" : "+v"(w1r[kk]));

  const float b2r0 = vfb2[r0], b2r1 = vfb2[r1];
  const int c0 = (2 * l) & 15;  // even dx channel of row r0; r1 -> c0+1
  const float b0i = vfb0[ii], b1i = vfb1[ii];

  const float* Xb = xs + (size_t)b * 4096;
  float* yb = ybuf + (size_t)b * 16384;

  __syncthreads();

  // ---- initial condition MLP (one-time; sTA := sK[0..1], sTB := sH1) ----
  float* sTA = &sK[0][0];
  float* sTB = sH1;
  if (tid < 128) {
    float a = icb0[tid];
    const float* wr = icw0 + tid * 16;
#pragma unroll
    for (int k = 0; k < 16; ++k) a += wr[k] * Xb[k];
    sTA[tid] = softplus_fast(a);
  }
  __syncthreads();
  if (tid < 128) {
    float a = icb1[tid];
    const float* wr = icw1 + tid * 128;
    for (int k = 0; k < 128; ++k) a += wr[k] * sTA[k];
    sTB[tid] = softplus_fast(a);
  }
  __syncthreads();
  if (tid < 64) {
    float a = icb2[tid];
    const float* wr = icw2 + tid * 128;
    for (int k = 0; k < 128; ++k) a += wr[k] * sTB[k];
    sH2[tid] = a;  // temp broadcast slot
  }
  __syncthreads();
  float yreg = sH2[l];  // every wave holds y[l]
  if (w == 0) yb[l] = yreg;

  const float hstep = 1.f / 255.f;
  const float invh = 255.f;

#pragma unroll 1
  for (int t = 0; t < 255; ++t) {
    // per-lane x-channel pair (c0, c0+1): j-invariant dXdt basis in regs
    float2v xt = *(const float2v*)(Xb + t * 16 + c0);
    float2v xt1 = *(const float2v*)(Xb + (t + 1) * 16 + c0);
    float2v xtm = xt;
    if (t != 0) xtm = *(const float2v*)(Xb + (t - 1) * 16 + c0);
    const float u0 = xt.x - xt1.x, u1 = xt.y - xt1.y;       // (xi - xip1)
    const float dp0 = (xt1.x - xt.x) * invh;                 // dfull[t+1]
    const float dp1 = (xt1.y - xt.y) * invh;
    float di0 = (t == 0) ? dp0 : (xt.x - xtm.x) * invh;      // dfull[t]
    float di1 = (t == 0) ? dp1 : (xt.y - xtm.y) * invh;
#pragma unroll 1
    for (int j = 0; j < 6; ++j) {
      // ---- streamed W2 cols 72..89 (consumed in k-phase) ----
      const float* wr0 = vfw2 + (size_t)r0 * 128;
      const float* wr1 = vfw2 + (size_t)r1 * 128;
      float4v sa0 = *(const float4v*)(wr0 + 72);
      float4v sa1 = *(const float4v*)(wr0 + 76);
      float4v sa2 = *(const float4v*)(wr0 + 80);
      float4v sa3 = *(const float4v*)(wr0 + 84);
      float2v sa4 = *(const float2v*)(wr0 + 88);
      float4v sb0 = *(const float4v*)(wr1 + 72);
      float4v sb1 = *(const float4v*)(wr1 + 76);
      float4v sb2 = *(const float4v*)(wr1 + 80);
      float4v sb3 = *(const float4v*)(wr1 + 84);
      float2v sb4 = *(const float2v*)(wr1 + 88);
      // ---- stage input y_j: every wave, per-lane, wave-private buffer ----
      {
        float yt = yreg;
#pragma unroll
        for (int m = 0; m < 5; ++m)
          if (m < j) yt += hstep * Ac[j][m] * sK[m][l];
        sYtw[w][l] = yt;
      }
      asm volatile("s_waitcnt lgkmcnt(0)" ::: "memory");  // in-wave only
      // ---- dXdt(sc_j) in registers ----
      const float sc = SCv[j], s2 = sc * sc;
      const float a1 = (6.f * s2 - 6.f * sc) * invh;
      const float a2 = 3.f * s2 - 4.f * sc + 1.f;
      const float a3 = 3.f * s2 - 2.f * sc;
      const float dx0 = a1 * u0 + a2 * di0 + a3 * dp0;
      const float dx1 = a1 * u1 + a2 * di1 + a3 * dp1;
      // ---- h1 = softplus(W0 @ y + b0) ----
      {
        const float4v* yv = (const float4v*)(&sYtw[w][0] + q4 * 16);
        float4v y0 = yv[0], y1 = yv[1], y2 = yv[2], y3 = yv[3];
        float s = w0r[0] * y0.x + w0r[1] * y0.y + w0r[2] * y0.z +
                  w0r[3] * y0.w + w0r[4] * y1.x + w0r[5] * y1.y +
                  w0r[6] * y1.z + w0r[7] * y1.w + w0r[8] * y2.x +
                  w0r[9] * y2.y + w0r[10] * y2.z + w0r[11] * y2.w +
                  w0r[12] * y3.x + w0r[13] * y3.y + w0r[14] * y3.z +
                  w0r[15] * y3.w;
        s += __shfl_xor(s, 1);
        s += __shfl_xor(s, 2);
        if (q4 == 0) sH1[ii] = softplus_fast(s + b0i);
      }
      __syncthreads();
      // ---- h2 = softplus(W1 @ h1 + b1) ----
      {
        const float4v* hv = (const float4v*)(sH1 + q4 * 32);
        float s = 0.f;
#pragma unroll
        for (int kk = 0; kk < 8; ++kk) {
          float4v h = hv[kk];
          s += w1r[4 * kk] * h.x + w1r[4 * kk + 1] * h.y +
               w1r[4 * kk + 2] * h.z + w1r[4 * kk + 3] * h.w;
        }
        s += __shfl_xor(s, 1);
        s += __shfl_xor(s, 2);
        if (q4 == 0) sH2[ii] = softplus_fast(s + b1i);
      }
      __syncthreads();
      // ---- k: rows r0,r1 of A = tanh(W2 h2 + b2), * dx, reduce over c ----
      {
        const float4v* hv = (const float4v*)sH2;
        float s0 = 0.f, s1 = 0.f;
#pragma unroll
        for (int kk = 0; kk < 18; ++kk) {  // pinned cols 0..71
          float4v h = hv[kk];
          s0 += w2a[4 * kk] * h.x + w2a[4 * kk + 1] * h.y +
                w2a[4 * kk + 2] * h.z + w2a[4 * kk + 3] * h.w;
          s1 += w2b[4 * kk] * h.x + w2b[4 * kk + 1] * h.y +
                w2b[4 * kk + 2] * h.z + w2b[4 * kk + 3] * h.w;
        }
        {  // streamed cols 72..89
          float4v h0 = hv[18], h1 = hv[19], h2 = hv[20], h3 = hv[21];
          float2v h4 = *(const float2v*)(sH2 + 88);
          s0 += dot4(sa0, h0) + dot4(sa1, h1) + dot4(sa2, h2) +
                dot4(sa3, h3) + sa4.x * h4.x + sa4.y * h4.y;
          s1 += dot4(sb0, h0) + dot4(sb1, h1) + dot4(sb2, h2) +
                dot4(sb3, h3) + sb4.x * h4.x + sb4.y * h4.y;
        }
#pragma unroll 4
        for (int k2 = 0; k2 < 19; ++k2) {  // LDS cols 90..127, pairwise
          float2v hk = *(const float2v*)(sH2 + 90 + 2 * k2);
          float2v wlo = *(const float2v*)&sW2t[2 * k2][r0];
          float2v whi = *(const float2v*)&sW2t[2 * k2 + 1][r0];
          s0 += wlo.x * hk.x + whi.x * hk.y;
          s1 += wlo.y * hk.x + whi.y * hk.y;
        }
        float f = tanh_hw(s0 + b2r0) * dx0 + tanh_hw(s1 + b2r1) * dx1;
        f += __shfl_xor(f, 1);
        f += __shfl_xor(f, 2);
        f += __shfl_xor(f, 4);
        if ((tid & 7) == 0) sK[j][tid >> 3] = f;
      }
      __syncthreads();
    }
    // ---- y_{t+1}: every wave redundantly; wave0 dumps the state ----
    {
      float yn = yreg;
#pragma unroll
      for (int m = 0; m < 6; ++m) yn += hstep * BWv[m] * sK[m][l];
      yreg = yn;
      if (w == 0) yb[(size_t)(t + 1) * 64 + l] = yn;
    }
  }
}

// Parallel readout: one thread per (b,t): out6 = y @ ro^T + rob, 6D->SO(3).
__global__ __launch_bounds__(256) void readout(
    const float* __restrict__ ybuf, const float* __restrict__ row,
    const float* __restrict__ rob, float* __restrict__ out) {
  int idx = blockIdx.x * blockDim.x + threadIdx.x;  // b*256+t
  const float* y = ybuf + (size_t)idx * 64;
  float p[6];
#pragma unroll
  for (int o = 0; o < 6; ++o) {
    const float4v* rr = (const float4v*)(row + o * 64);
    const float4v* yv = (const float4v*)y;
    float s = 0.f;
#pragma unroll
    for (int k = 0; k < 16; ++k) s += dot4(rr[k], yv[k]);
    p[o] = s + rob[o];
  }
  float a1x = p[0], a1y = p[1], a1z = p[2];
  float a2x = p[3], a2y = p[4], a2z = p[5];
  float n1 = rsqrtf(a1x * a1x + a1y * a1y + a1z * a1z);
  float b1x = a1x * n1, b1y = a1y * n1, b1z = a1z * n1;
  float d = b1x * a2x + b1y * a2y + b1z * a2z;
  float px = a2x - d * b1x, py = a2y - d * b1y, pz = a2z - d * b1z;
  float n2 = rsqrtf(px * px + py * py + pz * pz);
  float b2x = px * n2, b2y = py * n2, b2z = pz * n2;
  float b3x = b1y * b2z - b1z * b2y;
  float b3y = b1z * b2x - b1x * b2z;
  float b3z = b1x * b2y - b1y * b2x;
  float* o = out + (size_t)idx * 9;
  o[0] = b1x; o[1] = b2x; o[2] = b3x;
  o[3] = b1y; o[4] = b2y; o[5] = b3y;
  o[6] = b1z; o[7] = b2z; o[8] = b3z;
}

extern "C" void kernel_launch(void* const* d_in, const int* in_sizes, int n_in,
                              void* d_out, int out_size, void* d_ws,
                              size_t ws_size, hipStream_t stream) {
  (void)in_sizes; (void)n_in; (void)out_size; (void)ws_size;
  const float* xs   = (const float*)d_in[0];
  const float* icw0 = (const float*)d_in[1];
  const float* icb0 = (const float*)d_in[2];
  const float* icw1 = (const float*)d_in[3];
  const float* icb1 = (const float*)d_in[4];
  const float* icw2 = (const float*)d_in[5];
  const float* icb2 = (const float*)d_in[6];
  const float* vfw0 = (const float*)d_in[7];
  const float* vfb0 = (const float*)d_in[8];
  const float* vfw1 = (const float*)d_in[9];
  const float* vfb1 = (const float*)d_in[10];
  const float* vfw2 = (const float*)d_in[11];
  const float* vfb2 = (const float*)d_in[12];
  const float* row  = (const float*)d_in[13];
  const float* rob  = (const float*)d_in[14];
  float* ybuf = (float*)d_ws;  // 64*256*64 floats = 4 MB

  hipLaunchKernelGGL(cde_main, dim3(64), dim3(512), 0, stream,
                     xs, icw0, icb0, icw1, icb1, icw2, icb2,
                     vfw0, vfb0, vfw1, vfb1, vfw2, vfb2, ybuf);
  hipLaunchKernelGGL(readout, dim3(64), dim3(256), 0, stream,
                     ybuf, row, rob, (float*)d_out);
}